// Round 2
// baseline (364.627 us; speedup 1.0000x reference)
//
#include <hip/hip_runtime.h>
#include <math.h>

#define C_DIM 2048
#define E_DIM 64
#define KC    128
#define TB    16     // tokens per block (K1)

// ---------------- K1: logits (fp64-accurate) + top-2 + softmax ----------------
// Layout: lane = q(0..15) expert-quad | s(0..3) token-slot. Thread computes
// 4 tokens (s*4+i) x 4 experts (4q+j). Waves split k (wave w owns k-slice
// [w*32, w*32+32) of each KC=128 tile); fp64 partials reduced via LDS at end.
// w tile is XOR-swizzled in LDS: phys = e*128 + (k ^ 4*((e>>2)&7)) -> both the
// staging b128 writes and the per-quad b128 reads are 2-way (free).
// x is read straight from global (16 lanes share an address -> broadcast).
__launch_bounds__(256)
__global__ void k_logits_top2(const float* __restrict__ x, const float* __restrict__ w,
                              int* __restrict__ idx0, int* __restrict__ idx1,
                              float* __restrict__ probs, int N)
{
    __shared__ float lds[E_DIM * KC];   // 32 KB: w tile; aliased as double[4][16][64] for reduce

    const int tid  = threadIdx.x;
    const int lane = tid & 63;
    const int wid  = tid >> 6;
    const int q    = lane & 15;
    const int s    = lane >> 4;
    const int t0   = blockIdx.x * TB;
    const int xr   = 4 * (q & 7);       // k-xor for this thread's expert quad

    double acc[4][4];
#pragma unroll
    for (int i = 0; i < 4; ++i)
#pragma unroll
        for (int j = 0; j < 4; ++j) acc[i][j] = 0.0;

    const float* xbase = x + (size_t)(t0 + s * 4) * C_DIM;

    for (int kb = 0; kb < C_DIM; kb += KC) {
        __syncthreads();
        // stage w tile (swizzled). 256 threads x 8 float4 = 64e x 128k.
#pragma unroll
        for (int r = 0; r < 8; ++r) {
            int i  = tid + 256 * r;
            int e  = i >> 5;
            int k4 = (i & 31) * 4;
            float4 v = *(const float4*)(w + (size_t)e * C_DIM + kb + k4);
            int sw = 4 * ((e >> 2) & 7);
            *(float4*)(&lds[e * KC + (k4 ^ sw)]) = v;
        }
        __syncthreads();

        const int kl0 = wid * 32;   // this wave's k-slice within the tile
#pragma unroll
        for (int c = 0; c < 2; ++c) {
            const int kl = kl0 + 16 * c;
            // 4 experts x 16 k of w fragments (64 VGPRs, reused by 4 tokens)
            float4 wv[4][4];
#pragma unroll
            for (int j = 0; j < 4; ++j) {
                const float* wrow = &lds[(4 * q + j) * KC];
#pragma unroll
                for (int m = 0; m < 4; ++m)
                    wv[j][m] = *(const float4*)(wrow + ((kl + 4 * m) ^ xr));
            }
            const float* xp = xbase + kb + kl;
#pragma unroll
            for (int i = 0; i < 4; ++i) {
                const float* xt = xp + (size_t)i * C_DIM;
                float4 x0 = *(const float4*)(xt);
                float4 x1 = *(const float4*)(xt + 4);
                float4 x2 = *(const float4*)(xt + 8);
                float4 x3 = *(const float4*)(xt + 12);
#pragma unroll
                for (int j = 0; j < 4; ++j) {
                    // 16-term fp32 fma chain (err ~1e-8), then one fp64 add
                    float f;
                    f = x0.x * wv[j][0].x;
                    f = fmaf(x0.y, wv[j][0].y, f);
                    f = fmaf(x0.z, wv[j][0].z, f);
                    f = fmaf(x0.w, wv[j][0].w, f);
                    f = fmaf(x1.x, wv[j][1].x, f);
                    f = fmaf(x1.y, wv[j][1].y, f);
                    f = fmaf(x1.z, wv[j][1].z, f);
                    f = fmaf(x1.w, wv[j][1].w, f);
                    f = fmaf(x2.x, wv[j][2].x, f);
                    f = fmaf(x2.y, wv[j][2].y, f);
                    f = fmaf(x2.z, wv[j][2].z, f);
                    f = fmaf(x2.w, wv[j][2].w, f);
                    f = fmaf(x3.x, wv[j][3].x, f);
                    f = fmaf(x3.y, wv[j][3].y, f);
                    f = fmaf(x3.z, wv[j][3].z, f);
                    f = fmaf(x3.w, wv[j][3].w, f);
                    acc[i][j] += (double)f;
                }
            }
        }
    }

    // ---- cross-wave fp64 reduction through aliased LDS ----
    __syncthreads();
    double* dbuf = (double*)lds;   // [4 waves][16 tokens][64 experts] = 32 KB
#pragma unroll
    for (int i = 0; i < 4; ++i) {
        int idx = wid * 1024 + (s * 4 + i) * 64 + 4 * q;
        *(double2*)&dbuf[idx]     = make_double2(acc[i][0], acc[i][1]);
        *(double2*)&dbuf[idx + 2] = make_double2(acc[i][2], acc[i][3]);
    }
    __syncthreads();

    // ---- top-2 over 64 experts (lane = expert); wave wid does tokens wid*4.. ----
#pragma unroll
    for (int ti = 0; ti < 4; ++ti) {
        int t = wid * 4 + ti;
        double v = dbuf[t * 64 + lane] + dbuf[1024 + t * 64 + lane]
                 + dbuf[2048 + t * 64 + lane] + dbuf[3072 + t * 64 + lane];
        double a = v; int ix = lane;
#pragma unroll
        for (int off = 32; off > 0; off >>= 1) {
            double ov = __shfl_down(a, off, 64);
            int    oi = __shfl_down(ix, off, 64);
            if (ov > a || (ov == a && oi < ix)) { a = ov; ix = oi; }
        }
        int    i1 = __shfl(ix, 0, 64);
        double v1 = __shfl(a, 0, 64);

        a  = (lane == i1) ? -1e300 : v;
        ix = lane;
#pragma unroll
        for (int off = 32; off > 0; off >>= 1) {
            double ov = __shfl_down(a, off, 64);
            int    oi = __shfl_down(ix, off, 64);
            if (ov > a || (ov == a && oi < ix)) { a = ov; ix = oi; }
        }
        int    i2 = __shfl(ix, 0, 64);
        double v2 = __shfl(a, 0, 64);

        if (lane == 0) {
            int n = t0 + t;
            float d  = (float)(v2 - v1);              // <= 0
            float p0 = 1.0f / (1.0f + expf(d));
            idx0[n] = i1;
            idx1[n] = i2;
            probs[2 * n]     = p0;
            probs[2 * n + 1] = 1.0f - p0;
        }
    }
}

// ---------------- K2: per-expert rank scan, 1 wave per expert, zero barriers ----------------
__launch_bounds__(64)
__global__ void k_scan(const int* __restrict__ idx0, const int* __restrict__ idx1,
                       int* __restrict__ r0, int* __restrict__ r1, int N)
{
    const int e    = blockIdx.x;
    const int lane = threadIdx.x;
    const unsigned long long lt = (1ull << lane) - 1ull;
    int running = 0;

    for (int pass = 0; pass < 2; ++pass) {
        const int* idx = pass ? idx1 : idx0;
        int*       r   = pass ? r1   : r0;
        for (int base = 0; base < N; base += 512) {
            int v[8];
#pragma unroll
            for (int j = 0; j < 8; ++j) v[j] = idx[base + j * 64 + lane];
#pragma unroll
            for (int j = 0; j < 8; ++j) {
                bool p = (v[j] == e);
                unsigned long long b = __ballot(p);
                if (p) r[base + j * 64 + lane] = running + __popcll(b & lt);
                running += __popcll(b);
            }
        }
    }
}

// ---------------- K3: one-hot capacity mask + tail outputs (fused) ----------------
__launch_bounds__(256)
__global__ void k_mask_tail(const int* __restrict__ idx0, const int* __restrict__ idx1,
                            const int* __restrict__ r0, const int* __restrict__ r1,
                            const float* __restrict__ probs,
                            float* __restrict__ out, int N, int cap)
{
    int f = blockIdx.x * 256 + threadIdx.x;   // float4 index, total N*32
    int n   = f >> 5;
    int rem = (f & 31) * 4;       // 0..124 within the token's 128 floats
    int k   = rem >> 6;           // 0 or 1
    int e0  = rem & 63;
    int ix = k ? idx1[n] : idx0[n];
    int rr = k ? r1[n]   : r0[n];
    float val = (rr < cap) ? 1.0f : 0.0f;
    float4 o = make_float4(0.f, 0.f, 0.f, 0.f);
    int d = ix - e0;
    if (d >= 0 && d < 4) ((float*)&o)[d] = val;
    *(float4*)(out + (size_t)f * 4) = o;

    size_t base = (size_t)2 * N * E_DIM;
    if (f < 2 * N) {
        int n2 = f >> 1;
        int k2 = f & 1;
        int ix2 = k2 ? idx1[n2] : idx0[n2];
        int rr2 = k2 ? r1[n2]   : r0[n2];
        float p = probs[f];
        out[base + f]         = (rr2 < cap) ? p : 0.0f;   // router_probs_masked
        out[base + 2 * N + f] = (float)ix2;               // top_k_indices
        out[base + 4 * N + f] = (float)rr2;               // final_rank
    }
    if (f == 0) out[base + 6 * N] = (float)cap;           // exp_capacity
}

extern "C" void kernel_launch(void* const* d_in, const int* in_sizes, int n_in,
                              void* d_out, int out_size, void* d_ws, size_t ws_size,
                              hipStream_t stream)
{
    const float* x  = (const float*)d_in[0];
    const float* wg = (const float*)d_in[1];
    const int N = in_sizes[0] / C_DIM;   // 16384 tokens

    // workspace layout (24*N bytes = 384 KB)
    char* ws = (char*)d_ws;
    int*   idx0  = (int*)ws;
    int*   idx1  = idx0 + N;
    float* probs = (float*)(idx1 + N);
    int*   r0    = (int*)(probs + 2 * N);
    int*   r1    = r0 + N;

    float* out = (float*)d_out;

    int cap = (int)((long long)2 * 2 * N / E_DIM);   // TOP_K * EVAL_CAPACITY * N / E
    if (cap < 4) cap = 4;

    k_logits_top2<<<N / TB, 256, 0, stream>>>(x, wg, idx0, idx1, probs, N);
    k_scan<<<E_DIM, 64, 0, stream>>>(idx0, idx1, r0, r1, N);
    k_mask_tail<<<(N * 32) / 256, 256, 0, stream>>>(idx0, idx1, r0, r1, probs, out, N, cap);
}